// Round 1
// baseline (362.798 us; speedup 1.0000x reference)
//
#include <hip/hip_runtime.h>
#include <hip/hip_bf16.h>

typedef __attribute__((ext_vector_type(8))) short bf16x8;
typedef __attribute__((ext_vector_type(4))) float f32x4;

__device__ inline unsigned short f2bf(float f) {
  union { float f; unsigned int u; } v; v.f = f;
  unsigned int u = v.u;
  unsigned int r = (u + 0x7fffu + ((u >> 16) & 1u)) >> 16;
  return (unsigned short)r;
}

__global__ __launch_bounds__(256) void conv_f32_bf16(const float* __restrict__ src,
                                                     unsigned short* __restrict__ dst, int n) {
  int i = (blockIdx.x * 256 + threadIdx.x) * 4;
  if (i + 3 < n) {
    float4 v = *(const float4*)(src + i);
    ushort4 o;
    o.x = f2bf(v.x); o.y = f2bf(v.y); o.z = f2bf(v.z); o.w = f2bf(v.w);
    *(ushort4*)(dst + i) = o;
  }
}

// C[M,N] = A[M,K] @ W[N,K]^T  (bf16 in, fp32 acc). If Of != nullptr: fp32 out + bias.
__global__ __launch_bounds__(256) void gemm_nt(const unsigned short* __restrict__ A,
                                               const unsigned short* __restrict__ W,
                                               unsigned short* __restrict__ Obf,
                                               float* __restrict__ Of,
                                               const float* __restrict__ bias,
                                               int M, int N, int K) {
  __shared__ __align__(16) unsigned short As[64][72];  // pitch 72: 2-way bank alias only
  __shared__ __align__(16) unsigned short Ws[64][72];
  int tid = threadIdx.x;
  int wave = tid >> 6, lane = tid & 63;
  int lane15 = lane & 15, quad = lane >> 4;
  int wm = (wave >> 1) * 32, wn = (wave & 1) * 32;
  int m0 = blockIdx.x * 64, n0 = blockIdx.y * 64;
  f32x4 acc[2][2];
#pragma unroll
  for (int i = 0; i < 2; i++)
#pragma unroll
    for (int j = 0; j < 2; j++) acc[i][j] = (f32x4){0.f, 0.f, 0.f, 0.f};

  for (int k0 = 0; k0 < K; k0 += 64) {
    __syncthreads();
#pragma unroll
    for (int i = 0; i < 2; i++) {
      int c = tid + 256 * i;
      int row = c >> 3, col = (c & 7) * 8;
      *(uint4*)&As[row][col] = *(const uint4*)&A[(size_t)(m0 + row) * K + k0 + col];
      *(uint4*)&Ws[row][col] = *(const uint4*)&W[(size_t)(n0 + row) * K + k0 + col];
    }
    __syncthreads();
#pragma unroll
    for (int ks = 0; ks < 64; ks += 32) {
      bf16x8 a0 = *(const bf16x8*)&As[wm + lane15][ks + quad * 8];
      bf16x8 a1 = *(const bf16x8*)&As[wm + 16 + lane15][ks + quad * 8];
      bf16x8 b0 = *(const bf16x8*)&Ws[wn + lane15][ks + quad * 8];
      bf16x8 b1 = *(const bf16x8*)&Ws[wn + 16 + lane15][ks + quad * 8];
      acc[0][0] = __builtin_amdgcn_mfma_f32_16x16x32_bf16(a0, b0, acc[0][0], 0, 0, 0);
      acc[0][1] = __builtin_amdgcn_mfma_f32_16x16x32_bf16(a0, b1, acc[0][1], 0, 0, 0);
      acc[1][0] = __builtin_amdgcn_mfma_f32_16x16x32_bf16(a1, b0, acc[1][0], 0, 0, 0);
      acc[1][1] = __builtin_amdgcn_mfma_f32_16x16x32_bf16(a1, b1, acc[1][1], 0, 0, 0);
    }
  }
  // C/D layout: row = quad*4 + r, col = lane15 (verified m89/m91)
#pragma unroll
  for (int mt = 0; mt < 2; mt++)
#pragma unroll
    for (int nt = 0; nt < 2; nt++) {
      int row = m0 + wm + mt * 16 + quad * 4;
      int col = n0 + wn + nt * 16 + lane15;
#pragma unroll
      for (int r = 0; r < 4; r++) {
        float v = acc[mt][nt][r];
        if (Of) Of[(size_t)(row + r) * N + col] = v + bias[col];
        else    Obf[(size_t)(row + r) * N + col] = f2bf(v);
      }
    }
}

// Flash attention: grid (qtile=32, bh=32); block 256 = 4 waves, 64 Q rows/block,
// 16 Q rows/wave; KV tile 64; causal skip of whole tiles.
__global__ __launch_bounds__(256) void attn(const unsigned short* __restrict__ Q,
                                            const unsigned short* __restrict__ Kg,
                                            const unsigned short* __restrict__ Vg,
                                            unsigned short* __restrict__ ctx) {
  __shared__ __align__(16) unsigned short Ks[64][72];
  __shared__ __align__(16) unsigned short Vt[64][72];  // transposed: Vt[d][k]
  __shared__ __align__(16) unsigned short Ps[64][72];
  const int Nn = 2048, Dm = 1024;
  int tid = threadIdx.x;
  int wave = tid >> 6, lane = tid & 63;
  int lane15 = lane & 15, quad = lane >> 4;
  int bh = blockIdx.y, b = bh >> 4, h = bh & 15;
  int qtile = blockIdx.x, qbase = qtile * 64;
  const float scale = 0.022097086912079608f;  // 1/sqrt(2048)

  const unsigned short* qptr = Q + (size_t)(b * Nn + qbase + wave * 16 + lane15) * Dm + h * 64;
  bf16x8 qa0 = *(const bf16x8*)(qptr + quad * 8);
  bf16x8 qa1 = *(const bf16x8*)(qptr + 32 + quad * 8);

  f32x4 oacc[4];
#pragma unroll
  for (int i = 0; i < 4; i++) oacc[i] = (f32x4){0.f, 0.f, 0.f, 0.f};
  float mrow[4] = {-1e30f, -1e30f, -1e30f, -1e30f};
  float lrow[4] = {0.f, 0.f, 0.f, 0.f};
  int qg = qbase + wave * 16 + quad * 4;

  for (int t = 0; t <= qtile; t++) {
    int k0 = t * 64;
    __syncthreads();
#pragma unroll
    for (int i = 0; i < 2; i++) {
      int c = tid + 256 * i;
      int kr = c >> 3, d0 = (c & 7) * 8;
      size_t g = (size_t)(b * Nn + k0 + kr) * Dm + h * 64 + d0;
      *(uint4*)&Ks[kr][d0] = *(const uint4*)&Kg[g];
      uint4 vv = *(const uint4*)&Vg[g];
      unsigned short* pv = (unsigned short*)&vv;
#pragma unroll
      for (int j = 0; j < 8; j++) Vt[d0 + j][kr] = pv[j];
    }
    __syncthreads();

    // S = Q K^T : wave's 16 rows x 64 cols
    f32x4 s[4];
#pragma unroll
    for (int ct = 0; ct < 4; ct++) {
      bf16x8 kb0 = *(const bf16x8*)&Ks[ct * 16 + lane15][quad * 8];
      bf16x8 kb1 = *(const bf16x8*)&Ks[ct * 16 + lane15][32 + quad * 8];
      f32x4 z = (f32x4){0.f, 0.f, 0.f, 0.f};
      z = __builtin_amdgcn_mfma_f32_16x16x32_bf16(qa0, kb0, z, 0, 0, 0);
      z = __builtin_amdgcn_mfma_f32_16x16x32_bf16(qa1, kb1, z, 0, 0, 0);
      s[ct] = z;
    }

    // online softmax per row (rows live on 16-lane groups; quad-local shfl_xor)
#pragma unroll
    for (int r = 0; r < 4; r++) {
      float mx = -1e30f;
#pragma unroll
      for (int ct = 0; ct < 4; ct++) {
        int kg = k0 + ct * 16 + lane15;
        float sv = s[ct][r] * scale;
        if (kg > qg + r) sv = -1e30f;
        s[ct][r] = sv;
        mx = fmaxf(mx, sv);
      }
#pragma unroll
      for (int off = 1; off < 16; off <<= 1) mx = fmaxf(mx, __shfl_xor(mx, off));
      float mn = fmaxf(mrow[r], mx);
      float sum = 0.f;
#pragma unroll
      for (int ct = 0; ct < 4; ct++) {
        float p = __expf(s[ct][r] - mn);
        s[ct][r] = p;
        sum += p;
      }
#pragma unroll
      for (int off = 1; off < 16; off <<= 1) sum += __shfl_xor(sum, off);
      float alpha = __expf(mrow[r] - mn);
      lrow[r] = lrow[r] * alpha + sum;
      mrow[r] = mn;
#pragma unroll
      for (int ct = 0; ct < 4; ct++) oacc[ct][r] *= alpha;
    }

    // P: C-layout regs -> LDS -> A-layout frags (m120 pattern)
#pragma unroll
    for (int ct = 0; ct < 4; ct++)
#pragma unroll
      for (int r = 0; r < 4; r++)
        Ps[wave * 16 + quad * 4 + r][ct * 16 + lane15] = f2bf(s[ct][r]);
    __syncthreads();

    bf16x8 pa0 = *(const bf16x8*)&Ps[wave * 16 + lane15][quad * 8];
    bf16x8 pa1 = *(const bf16x8*)&Ps[wave * 16 + lane15][32 + quad * 8];
#pragma unroll
    for (int ct = 0; ct < 4; ct++) {
      bf16x8 vb0 = *(const bf16x8*)&Vt[ct * 16 + lane15][quad * 8];
      bf16x8 vb1 = *(const bf16x8*)&Vt[ct * 16 + lane15][32 + quad * 8];
      oacc[ct] = __builtin_amdgcn_mfma_f32_16x16x32_bf16(pa0, vb0, oacc[ct], 0, 0, 0);
      oacc[ct] = __builtin_amdgcn_mfma_f32_16x16x32_bf16(pa1, vb1, oacc[ct], 0, 0, 0);
    }
  }

#pragma unroll
  for (int r = 0; r < 4; r++) {
    float inv = 1.0f / lrow[r];
#pragma unroll
    for (int ct = 0; ct < 4; ct++) {
      size_t idx = (size_t)(b * Nn + qbase + wave * 16 + quad * 4 + r) * Dm + h * 64 + ct * 16 + lane15;
      ctx[idx] = f2bf(oacc[ct][r] * inv);
    }
  }
}

extern "C" void kernel_launch(void* const* d_in, const int* in_sizes, int n_in,
                              void* d_out, int out_size, void* d_ws, size_t ws_size,
                              hipStream_t stream) {
  const float* x  = (const float*)d_in[0];
  const float* Wq = (const float*)d_in[1];
  const float* Wk = (const float*)d_in[2];
  const float* Wv = (const float*)d_in[3];
  const float* Wo = (const float*)d_in[4];
  const float* bo = (const float*)d_in[5];
  float* out = (float*)d_out;
  char* ws = (char*)d_ws;
  const size_t MB = 1024 * 1024;
  unsigned short* xb   = (unsigned short*)(ws);            //  8 MB  x   bf16 [4096,1024]
  unsigned short* wqb  = (unsigned short*)(ws +  8 * MB);  //  2 MB
  unsigned short* wkb  = (unsigned short*)(ws + 10 * MB);
  unsigned short* wvb  = (unsigned short*)(ws + 12 * MB);
  unsigned short* wob  = (unsigned short*)(ws + 14 * MB);
  unsigned short* Qb   = (unsigned short*)(ws + 16 * MB);  //  8 MB each
  unsigned short* Kb   = (unsigned short*)(ws + 24 * MB);
  unsigned short* Vb   = (unsigned short*)(ws + 32 * MB);
  unsigned short* ctxb = (unsigned short*)(ws + 40 * MB);  // total 48 MB

  conv_f32_bf16<<<4096, 256, 0, stream>>>(x, xb, 4194304);
  conv_f32_bf16<<<1024, 256, 0, stream>>>(Wq, wqb, 1048576);
  conv_f32_bf16<<<1024, 256, 0, stream>>>(Wk, wkb, 1048576);
  conv_f32_bf16<<<1024, 256, 0, stream>>>(Wv, wvb, 1048576);
  conv_f32_bf16<<<1024, 256, 0, stream>>>(Wo, wob, 1048576);

  dim3 g(64, 16), blk(256, 1, 1);
  gemm_nt<<<g, blk, 0, stream>>>(xb, wqb, Qb, nullptr, nullptr, 4096, 1024, 1024);
  gemm_nt<<<g, blk, 0, stream>>>(xb, wkb, Kb, nullptr, nullptr, 4096, 1024, 1024);
  gemm_nt<<<g, blk, 0, stream>>>(xb, wvb, Vb, nullptr, nullptr, 4096, 1024, 1024);
  attn<<<dim3(32, 32, 1), blk, 0, stream>>>(Qb, Kb, Vb, ctxb);
  gemm_nt<<<g, blk, 0, stream>>>(ctxb, wob, nullptr, out, bo, 4096, 1024, 1024);
}

// Round 2
// 214.959 us; speedup vs baseline: 1.6878x; 1.6878x over previous
//
#include <hip/hip_runtime.h>
#include <hip/hip_bf16.h>

typedef __attribute__((ext_vector_type(8))) short bf16x8;
typedef __attribute__((ext_vector_type(4))) float f32x4;
typedef unsigned short u16;

__device__ __forceinline__ u16 f2bf(float f) {  // RNE
  union { float f; unsigned int u; } v; v.f = f;
  return (u16)((v.u + 0x7fffu + ((v.u >> 16) & 1u)) >> 16);
}
__device__ __forceinline__ u16 f2bf_fast(float f) {  // round-half-up (P matrix only)
  union { float f; unsigned int u; } v; v.f = f;
  return (u16)((v.u + 0x8000u) >> 16);
}

#define GLOAD_LDS16(g, l) __builtin_amdgcn_global_load_lds( \
    (const __attribute__((address_space(1))) void*)(g),     \
    (__attribute__((address_space(3))) void*)(l), 16, 0, 0)

// ---------------- fp32 -> bf16 conversion, all tensors in one launch ----------------
__global__ __launch_bounds__(256) void conv_all(const float* __restrict__ x,
                                                const float* __restrict__ wq, const float* __restrict__ wk,
                                                const float* __restrict__ wv, const float* __restrict__ wo,
                                                u16* __restrict__ xb, u16* __restrict__ qo, u16* __restrict__ ko,
                                                u16* __restrict__ vo, u16* __restrict__ oo) {
  int y = blockIdx.y;
  const float* src; u16* dst;
  if (y < 4) { src = x + (size_t)y * 1048576; dst = xb + (size_t)y * 1048576; }
  else if (y == 4) { src = wq; dst = qo; }
  else if (y == 5) { src = wk; dst = ko; }
  else if (y == 6) { src = wv; dst = vo; }
  else { src = wo; dst = oo; }
  int i = (blockIdx.x * 256 + threadIdx.x) * 4;
  float4 v = *(const float4*)(src + i);
  ushort4 o;
  o.x = f2bf(v.x); o.y = f2bf(v.y); o.z = f2bf(v.z); o.w = f2bf(v.w);
  *(ushort4*)(dst + i) = o;
}

// ---------------- shared GEMM mainloop: C128x128 = A[M,K] @ W[N,K]^T ----------------
// LDS layout: unpadded [128][64], 16B chunks XOR-swizzled by (row&7) -> conflict-free
// b128 frag reads AND valid global_load_lds (lane-linear LDS dest).
__device__ __forceinline__ void gemm_main(const u16* __restrict__ A, const u16* __restrict__ W,
                                          u16* As, u16* Bs, int m0, int n0, int K,
                                          f32x4 acc[4][4]) {
  int tid = threadIdx.x, wave = tid >> 6, lane = tid & 63;
  int lane15 = lane & 15, quad = lane >> 4;
  int wm = (wave >> 1) * 64, wn = (wave & 1) * 64;
  for (int k0 = 0; k0 < K; k0 += 64) {
    __syncthreads();
#pragma unroll
    for (int i = 0; i < 4; i++) {
      int rbase = wave * 32 + i * 8;
      int rloc = rbase + (lane >> 3);
      int ca = ((lane & 7) ^ (rloc & 7)) * 8;
      GLOAD_LDS16(A + (size_t)(m0 + rloc) * K + k0 + ca, As + rbase * 64);
      GLOAD_LDS16(W + (size_t)(n0 + rloc) * K + k0 + ca, Bs + rbase * 64);
    }
    __syncthreads();
#pragma unroll
    for (int kc = 0; kc < 2; kc++) {
      bf16x8 a[4], b[4];
#pragma unroll
      for (int mi = 0; mi < 4; mi++) {
        int m = wm + mi * 16 + lane15;
        a[mi] = *(const bf16x8*)(As + m * 64 + (((kc * 4 + quad) ^ (m & 7)) * 8));
      }
#pragma unroll
      for (int ni = 0; ni < 4; ni++) {
        int n = wn + ni * 16 + lane15;
        b[ni] = *(const bf16x8*)(Bs + n * 64 + (((kc * 4 + quad) ^ (n & 7)) * 8));
      }
#pragma unroll
      for (int mi = 0; mi < 4; mi++)
#pragma unroll
        for (int ni = 0; ni < 4; ni++)
          acc[mi][ni] = __builtin_amdgcn_mfma_f32_16x16x32_bf16(a[mi], b[ni], acc[mi][ni], 0, 0, 0);
    }
  }
}

// QKV fused: grid (32, 8, 3). z=0 -> Q natural bf16, z=1 -> K natural, z=2 -> V transposed [b,h,dh,n]
__global__ __launch_bounds__(256, 3) void gemm_qkv(const u16* __restrict__ xb,
                                                   const u16* __restrict__ wq, const u16* __restrict__ wk,
                                                   const u16* __restrict__ wv,
                                                   u16* __restrict__ Qb, u16* __restrict__ Kb,
                                                   u16* __restrict__ Vtg) {
  __shared__ __align__(16) u16 As[128 * 64];
  __shared__ __align__(16) u16 Bs[128 * 64];
  const int K = 1024;
  int z = blockIdx.z;
  const u16* W = (z == 0) ? wq : (z == 1) ? wk : wv;
  int m0 = blockIdx.x * 128, n0 = blockIdx.y * 128;
  f32x4 acc[4][4];
#pragma unroll
  for (int i = 0; i < 4; i++)
#pragma unroll
    for (int j = 0; j < 4; j++) acc[i][j] = (f32x4){0.f, 0.f, 0.f, 0.f};
  gemm_main(xb, W, As, Bs, m0, n0, K, acc);

  int tid = threadIdx.x, wave = tid >> 6, lane = tid & 63;
  int lane15 = lane & 15, quad = lane >> 4;
  int wm = (wave >> 1) * 64, wn = (wave & 1) * 64;
  if (z < 2) {
    u16* Out = z ? Kb : Qb;
#pragma unroll
    for (int mi = 0; mi < 4; mi++)
#pragma unroll
      for (int ni = 0; ni < 4; ni++) {
        int row = m0 + wm + mi * 16 + quad * 4;
        int col = n0 + wn + ni * 16 + lane15;
#pragma unroll
        for (int r = 0; r < 4; r++)
          Out[(size_t)(row + r) * 1024 + col] = f2bf(acc[mi][ni][r]);
      }
  } else {
#pragma unroll
    for (int mi = 0; mi < 4; mi++)
#pragma unroll
      for (int ni = 0; ni < 4; ni++) {
        int row = m0 + wm + mi * 16 + quad * 4;
        int col = n0 + wn + ni * 16 + lane15;
        int bb = row >> 11, nn = row & 2047;
        ushort4 o;
        o.x = f2bf(acc[mi][ni][0]); o.y = f2bf(acc[mi][ni][1]);
        o.z = f2bf(acc[mi][ni][2]); o.w = f2bf(acc[mi][ni][3]);
        *(ushort4*)&Vtg[(size_t)(bb * 1024 + col) * 2048 + nn] = o;
      }
  }
}

// Output projection: fp32 out + bias. grid (32, 8)
__global__ __launch_bounds__(256, 2) void gemm_out(const u16* __restrict__ A, const u16* __restrict__ W,
                                                   float* __restrict__ Of, const float* __restrict__ bias) {
  __shared__ __align__(16) u16 As[128 * 64];
  __shared__ __align__(16) u16 Bs[128 * 64];
  const int K = 1024;
  int m0 = blockIdx.x * 128, n0 = blockIdx.y * 128;
  f32x4 acc[4][4];
#pragma unroll
  for (int i = 0; i < 4; i++)
#pragma unroll
    for (int j = 0; j < 4; j++) acc[i][j] = (f32x4){0.f, 0.f, 0.f, 0.f};
  gemm_main(A, W, As, Bs, m0, n0, K, acc);

  int tid = threadIdx.x, wave = tid >> 6, lane = tid & 63;
  int lane15 = lane & 15, quad = lane >> 4;
  int wm = (wave >> 1) * 64, wn = (wave & 1) * 64;
#pragma unroll
  for (int mi = 0; mi < 4; mi++)
#pragma unroll
    for (int ni = 0; ni < 4; ni++) {
      int row = m0 + wm + mi * 16 + quad * 4;
      int col = n0 + wn + ni * 16 + lane15;
#pragma unroll
      for (int r = 0; r < 4; r++)
        Of[(size_t)(row + r) * 1024 + col] = acc[mi][ni][r] + bias[col];
    }
}

// ---------------- flash attention v2 ----------------
// grid (16, 32): qtile of 128 rows x (b,h). 4 waves, wave owns 32 q rows.
// KV tile 128. K/V^T staged by global_load_lds into XOR-swizzled unpadded LDS.
__global__ __launch_bounds__(256, 2) void attn2(const u16* __restrict__ Q, const u16* __restrict__ Kg,
                                                const u16* __restrict__ Vtg, u16* __restrict__ ctx) {
  __shared__ __align__(16) u16 KsL[128 * 64];   // [kv][dh], chunks ^(row&7)
  __shared__ __align__(16) u16 VtsL[64 * 128];  // [dh][kv], chunks ^(row&15)
  __shared__ __align__(16) u16 Ps[128][72];     // wave-private 32-row stripes, half-width P
  int tid = threadIdx.x, wave = tid >> 6, lane = tid & 63;
  int lane15 = lane & 15, quad = lane >> 4;
  int bh = blockIdx.y, b = bh >> 4, h = bh & 15;
  int qtile = blockIdx.x, qbase = qtile * 128;
  const float kSc = 0.022097086912079608f * 1.4426950408889634f;  // (1/sqrt(2048))*log2(e)

  bf16x8 qa[2][2];
#pragma unroll
  for (int mi = 0; mi < 2; mi++)
#pragma unroll
    for (int kc = 0; kc < 2; kc++)
      qa[mi][kc] = *(const bf16x8*)&Q[(size_t)(b * 2048 + qbase + wave * 32 + mi * 16 + lane15) * 1024 +
                                      h * 64 + kc * 32 + quad * 8];

  f32x4 oacc[2][4];
#pragma unroll
  for (int mi = 0; mi < 2; mi++)
#pragma unroll
    for (int c4 = 0; c4 < 4; c4++) oacc[mi][c4] = (f32x4){0.f, 0.f, 0.f, 0.f};
  float mrow[2][4], lrow[2][4];
#pragma unroll
  for (int mi = 0; mi < 2; mi++)
#pragma unroll
    for (int r = 0; r < 4; r++) { mrow[mi][r] = -3.0e38f; lrow[mi][r] = 0.f; }

  for (int t = 0; t <= qtile; ++t) {
    int k0 = t * 128;
    __syncthreads();
#pragma unroll
    for (int i = 0; i < 4; i++) {
      int rbase = wave * 32 + i * 8;
      int rk = rbase + (lane >> 3);
      int ca = ((lane & 7) ^ (rk & 7)) * 8;
      GLOAD_LDS16(&Kg[(size_t)(b * 2048 + k0 + rk) * 1024 + h * 64 + ca], KsL + rbase * 64);
      int vbase = wave * 16 + i * 4;
      int rv = vbase + (lane >> 4);
      int cv = ((lane & 15) ^ (rv & 15)) * 8;
      GLOAD_LDS16(&Vtg[(size_t)(b * 1024 + h * 64 + rv) * 2048 + k0 + cv], VtsL + vbase * 128);
    }
    __syncthreads();

    // ---- S = Q K^T (32q x 128kv per wave) ----
    f32x4 s[2][8];
#pragma unroll
    for (int ct = 0; ct < 8; ct++) {
      int kr = ct * 16 + lane15;
      bf16x8 kb0 = *(const bf16x8*)(KsL + kr * 64 + ((quad ^ (kr & 7)) * 8));
      bf16x8 kb1 = *(const bf16x8*)(KsL + kr * 64 + (((4 + quad) ^ (kr & 7)) * 8));
#pragma unroll
      for (int mi = 0; mi < 2; mi++) {
        f32x4 z = (f32x4){0.f, 0.f, 0.f, 0.f};
        z = __builtin_amdgcn_mfma_f32_16x16x32_bf16(qa[mi][0], kb0, z, 0, 0, 0);
        z = __builtin_amdgcn_mfma_f32_16x16x32_bf16(qa[mi][1], kb1, z, 0, 0, 0);
        s[mi][ct] = z;
      }
    }

    // ---- online softmax ----
    bool diag = (t == qtile);
#pragma unroll
    for (int mi = 0; mi < 2; mi++)
#pragma unroll
      for (int r = 0; r < 4; r++) {
        int qloc = wave * 32 + mi * 16 + quad * 4 + r;
        float mx = -3.0e38f;
        if (diag) {
#pragma unroll
          for (int ct = 0; ct < 8; ct++) {
            float sv = s[mi][ct][r] * kSc;
            if (ct * 16 + lane15 > qloc) sv = -3.0e38f;
            s[mi][ct][r] = sv; mx = fmaxf(mx, sv);
          }
        } else {
#pragma unroll
          for (int ct = 0; ct < 8; ct++) {
            float sv = s[mi][ct][r] * kSc;
            s[mi][ct][r] = sv; mx = fmaxf(mx, sv);
          }
        }
#pragma unroll
        for (int off = 1; off < 16; off <<= 1) mx = fmaxf(mx, __shfl_xor(mx, off));
        float mn = fmaxf(mrow[mi][r], mx);
        float sum = 0.f;
#pragma unroll
        for (int ct = 0; ct < 8; ct++) {
          float p = __builtin_amdgcn_exp2f(s[mi][ct][r] - mn);
          s[mi][ct][r] = p; sum += p;
        }
#pragma unroll
        for (int off = 1; off < 16; off <<= 1) sum += __shfl_xor(sum, off);
        float alpha = __builtin_amdgcn_exp2f(mrow[mi][r] - mn);
        lrow[mi][r] = lrow[mi][r] * alpha + sum;
        mrow[mi][r] = mn;
#pragma unroll
        for (int c4 = 0; c4 < 4; c4++) oacc[mi][c4][r] *= alpha;
      }

    // ---- PV in two kv-halves: P (C-layout) -> wave-private LDS -> A-frags ----
#pragma unroll
    for (int hf = 0; hf < 2; hf++) {
#pragma unroll
      for (int mi = 0; mi < 2; mi++)
#pragma unroll
        for (int ct = 0; ct < 4; ct++)
#pragma unroll
          for (int r = 0; r < 4; r++)
            Ps[wave * 32 + mi * 16 + quad * 4 + r][ct * 16 + lane15] = f2bf_fast(s[mi][hf * 4 + ct][r]);
      // wave-private region: no barrier; compiler inserts lgkm wait
#pragma unroll
      for (int kc = 0; kc < 2; kc++) {
        bf16x8 pa0 = *(const bf16x8*)&Ps[wave * 32 + lane15][kc * 32 + quad * 8];
        bf16x8 pa1 = *(const bf16x8*)&Ps[wave * 32 + 16 + lane15][kc * 32 + quad * 8];
        int cb = hf * 8 + kc * 4 + quad;  // kv chunk index 0..15
#pragma unroll
        for (int c4 = 0; c4 < 4; c4++) {
          int dh = c4 * 16 + lane15;
          bf16x8 vb = *(const bf16x8*)(VtsL + dh * 128 + ((cb ^ (dh & 15)) * 8));
          oacc[0][c4] = __builtin_amdgcn_mfma_f32_16x16x32_bf16(pa0, vb, oacc[0][c4], 0, 0, 0);
          oacc[1][c4] = __builtin_amdgcn_mfma_f32_16x16x32_bf16(pa1, vb, oacc[1][c4], 0, 0, 0);
        }
      }
    }
  }

#pragma unroll
  for (int mi = 0; mi < 2; mi++)
#pragma unroll
    for (int r = 0; r < 4; r++) {
      float inv = 1.0f / lrow[mi][r];
      int row = qbase + wave * 32 + mi * 16 + quad * 4 + r;
#pragma unroll
      for (int c4 = 0; c4 < 4; c4++)
        ctx[(size_t)(b * 2048 + row) * 1024 + h * 64 + c4 * 16 + lane15] = f2bf(oacc[mi][c4][r] * inv);
    }
}

extern "C" void kernel_launch(void* const* d_in, const int* in_sizes, int n_in,
                              void* d_out, int out_size, void* d_ws, size_t ws_size,
                              hipStream_t stream) {
  const float* x  = (const float*)d_in[0];
  const float* Wq = (const float*)d_in[1];
  const float* Wk = (const float*)d_in[2];
  const float* Wv = (const float*)d_in[3];
  const float* Wo = (const float*)d_in[4];
  const float* bo = (const float*)d_in[5];
  float* out = (float*)d_out;
  char* ws = (char*)d_ws;
  const size_t MB = 1024 * 1024;
  u16* xb   = (u16*)(ws);
  u16* wqb  = (u16*)(ws +  8 * MB);
  u16* wkb  = (u16*)(ws + 10 * MB);
  u16* wvb  = (u16*)(ws + 12 * MB);
  u16* wob  = (u16*)(ws + 14 * MB);
  u16* Qb   = (u16*)(ws + 16 * MB);
  u16* Kb   = (u16*)(ws + 24 * MB);
  u16* Vtg  = (u16*)(ws + 32 * MB);  // V^T: [b,h,dh,n]
  u16* ctxb = (u16*)(ws + 40 * MB);

  conv_all<<<dim3(1024, 8), 256, 0, stream>>>(x, Wq, Wk, Wv, Wo, xb, wqb, wkb, wvb, wob);
  gemm_qkv<<<dim3(32, 8, 3), 256, 0, stream>>>(xb, wqb, wkb, wvb, Qb, Kb, Vtg);
  attn2<<<dim3(16, 32), 256, 0, stream>>>(Qb, Kb, Vtg, ctxb);
  gemm_out<<<dim3(32, 8), 256, 0, stream>>>(ctxb, wob, out, bo);
}

// Round 4
// 179.414 us; speedup vs baseline: 2.0221x; 1.1981x over previous
//
#include <hip/hip_runtime.h>
#include <hip/hip_bf16.h>

typedef __attribute__((ext_vector_type(8))) short bf16x8;
typedef __attribute__((ext_vector_type(4))) float f32x4;
typedef unsigned short u16;

__device__ __forceinline__ u16 f2bf(float f) {  // RNE
  union { float f; unsigned int u; } v; v.f = f;
  return (u16)((v.u + 0x7fffu + ((v.u >> 16) & 1u)) >> 16);
}
// pack two floats -> two bf16 in one u32 (round-half-up; P matrix only)
__device__ __forceinline__ unsigned int pack_bf2(float f0, float f1) {
  union { float f; unsigned int u; } a, b; a.f = f0; b.f = f1;
  return __builtin_amdgcn_perm(b.u + 0x8000u, a.u + 0x8000u, 0x07060302u);
}

#define GLOAD_LDS16(g, l) __builtin_amdgcn_global_load_lds( \
    (const __attribute__((address_space(1))) void*)(g),     \
    (__attribute__((address_space(3))) void*)(l), 16, 0, 0)

// ---------------- fp32 -> bf16 conversion, all tensors in one launch ----------------
__global__ __launch_bounds__(256) void conv_all(const float* __restrict__ x,
                                                const float* __restrict__ wq, const float* __restrict__ wk,
                                                const float* __restrict__ wv, const float* __restrict__ wo,
                                                u16* __restrict__ xb, u16* __restrict__ qo, u16* __restrict__ ko,
                                                u16* __restrict__ vo, u16* __restrict__ oo) {
  int y = blockIdx.y;
  const float* src; u16* dst;
  if (y < 4) { src = x + (size_t)y * 1048576; dst = xb + (size_t)y * 1048576; }
  else if (y == 4) { src = wq; dst = qo; }
  else if (y == 5) { src = wk; dst = ko; }
  else if (y == 6) { src = wv; dst = vo; }
  else { src = wo; dst = oo; }
  int i = (blockIdx.x * 256 + threadIdx.x) * 4;
  float4 v = *(const float4*)(src + i);
  ushort4 o;
  o.x = f2bf(v.x); o.y = f2bf(v.y); o.z = f2bf(v.z); o.w = f2bf(v.w);
  *(ushort4*)(dst + i) = o;
}

// ---------------- shared GEMM mainloop (128M x 128N): C = A[M,K] @ W[N,K]^T ----------------
__device__ __forceinline__ void gemm_main(const u16* __restrict__ A, const u16* __restrict__ W,
                                          u16* As, u16* Bs, int m0, int n0, int K,
                                          f32x4 acc[4][4]) {
  int tid = threadIdx.x, wave = tid >> 6, lane = tid & 63;
  int lane15 = lane & 15, quad = lane >> 4;
  int wm = (wave >> 1) * 64, wn = (wave & 1) * 64;
  for (int k0 = 0; k0 < K; k0 += 64) {
    __syncthreads();
#pragma unroll
    for (int i = 0; i < 4; i++) {
      int rbase = wave * 32 + i * 8;
      int rloc = rbase + (lane >> 3);
      int ca = ((lane & 7) ^ (rloc & 7)) * 8;
      GLOAD_LDS16(A + (size_t)(m0 + rloc) * K + k0 + ca, As + rbase * 64);
      GLOAD_LDS16(W + (size_t)(n0 + rloc) * K + k0 + ca, Bs + rbase * 64);
    }
    __syncthreads();
#pragma unroll
    for (int kc = 0; kc < 2; kc++) {
      bf16x8 a[4], b[4];
#pragma unroll
      for (int mi = 0; mi < 4; mi++) {
        int m = wm + mi * 16 + lane15;
        a[mi] = *(const bf16x8*)(As + m * 64 + (((kc * 4 + quad) ^ (m & 7)) * 8));
      }
#pragma unroll
      for (int ni = 0; ni < 4; ni++) {
        int n = wn + ni * 16 + lane15;
        b[ni] = *(const bf16x8*)(Bs + n * 64 + (((kc * 4 + quad) ^ (n & 7)) * 8));
      }
#pragma unroll
      for (int mi = 0; mi < 4; mi++)
#pragma unroll
        for (int ni = 0; ni < 4; ni++)
          acc[mi][ni] = __builtin_amdgcn_mfma_f32_16x16x32_bf16(a[mi], b[ni], acc[mi][ni], 0, 0, 0);
    }
  }
}

// QKV fused: z=0 -> Q (pre-scaled by softmax scale * log2e), z=1 -> K, z=2 -> V^T [b,h,dh,n]
__global__ __launch_bounds__(256, 3) void gemm_qkv(const u16* __restrict__ xb,
                                                   const u16* __restrict__ wq, const u16* __restrict__ wk,
                                                   const u16* __restrict__ wv,
                                                   u16* __restrict__ Qb, u16* __restrict__ Kb,
                                                   u16* __restrict__ Vtg) {
  __shared__ __align__(16) u16 As[128 * 64];
  __shared__ __align__(16) u16 Bs[128 * 64];
  const int K = 1024;
  int z = blockIdx.z;
  const u16* W = (z == 0) ? wq : (z == 1) ? wk : wv;
  int m0 = blockIdx.x * 128, n0 = blockIdx.y * 128;
  f32x4 acc[4][4];
#pragma unroll
  for (int i = 0; i < 4; i++)
#pragma unroll
    for (int j = 0; j < 4; j++) acc[i][j] = (f32x4){0.f, 0.f, 0.f, 0.f};
  gemm_main(xb, W, As, Bs, m0, n0, K, acc);

  int tid = threadIdx.x, wave = tid >> 6, lane = tid & 63;
  int lane15 = lane & 15, quad = lane >> 4;
  int wm = (wave >> 1) * 64, wn = (wave & 1) * 64;
  const float kQs = 0.022097086912079608f * 1.4426950408889634f;  // 1/sqrt(2048)*log2(e)
  if (z < 2) {
    u16* Out = z ? Kb : Qb;
    float sc = z ? 1.0f : kQs;
#pragma unroll
    for (int mi = 0; mi < 4; mi++)
#pragma unroll
      for (int ni = 0; ni < 4; ni++) {
        int row = m0 + wm + mi * 16 + quad * 4;
        int col = n0 + wn + ni * 16 + lane15;
#pragma unroll
        for (int r = 0; r < 4; r++)
          Out[(size_t)(row + r) * 1024 + col] = f2bf(acc[mi][ni][r] * sc);
      }
  } else {
#pragma unroll
    for (int mi = 0; mi < 4; mi++)
#pragma unroll
      for (int ni = 0; ni < 4; ni++) {
        int row = m0 + wm + mi * 16 + quad * 4;
        int col = n0 + wn + ni * 16 + lane15;
        int bb = row >> 11, nn = row & 2047;
        ushort4 o;
        o.x = f2bf(acc[mi][ni][0]); o.y = f2bf(acc[mi][ni][1]);
        o.z = f2bf(acc[mi][ni][2]); o.w = f2bf(acc[mi][ni][3]);
        *(ushort4*)&Vtg[(size_t)(bb * 1024 + col) * 2048 + nn] = o;
      }
  }
}

// Output projection, 128M x 64N tiles -> 512 blocks (2/CU). fp32 out + bias.
__global__ __launch_bounds__(256, 2) void gemm_out(const u16* __restrict__ A, const u16* __restrict__ W,
                                                   float* __restrict__ Of, const float* __restrict__ bias) {
  __shared__ __align__(16) u16 As[128 * 64];
  __shared__ __align__(16) u16 Bs[64 * 64];
  const int K = 1024;
  int m0 = blockIdx.x * 128, n0 = blockIdx.y * 64;
  int tid = threadIdx.x, wave = tid >> 6, lane = tid & 63;
  int lane15 = lane & 15, quad = lane >> 4;
  int wm = (wave >> 1) * 64, wn = (wave & 1) * 32;
  f32x4 acc[4][2];
#pragma unroll
  for (int i = 0; i < 4; i++)
#pragma unroll
    for (int j = 0; j < 2; j++) acc[i][j] = (f32x4){0.f, 0.f, 0.f, 0.f};
  for (int k0 = 0; k0 < K; k0 += 64) {
    __syncthreads();
#pragma unroll
    for (int i = 0; i < 4; i++) {
      int rbase = wave * 32 + i * 8;
      int rloc = rbase + (lane >> 3);
      int ca = ((lane & 7) ^ (rloc & 7)) * 8;
      GLOAD_LDS16(A + (size_t)(m0 + rloc) * K + k0 + ca, As + rbase * 64);
    }
#pragma unroll
    for (int i = 0; i < 2; i++) {
      int rbase = wave * 16 + i * 8;
      int rloc = rbase + (lane >> 3);
      int ca = ((lane & 7) ^ (rloc & 7)) * 8;
      GLOAD_LDS16(W + (size_t)(n0 + rloc) * K + k0 + ca, Bs + rbase * 64);
    }
    __syncthreads();
#pragma unroll
    for (int kc = 0; kc < 2; kc++) {
      bf16x8 a[4], b[2];
#pragma unroll
      for (int mi = 0; mi < 4; mi++) {
        int m = wm + mi * 16 + lane15;
        a[mi] = *(const bf16x8*)(As + m * 64 + (((kc * 4 + quad) ^ (m & 7)) * 8));
      }
#pragma unroll
      for (int ni = 0; ni < 2; ni++) {
        int n = wn + ni * 16 + lane15;
        b[ni] = *(const bf16x8*)(Bs + n * 64 + (((kc * 4 + quad) ^ (n & 7)) * 8));
      }
#pragma unroll
      for (int mi = 0; mi < 4; mi++)
#pragma unroll
        for (int ni = 0; ni < 2; ni++)
          acc[mi][ni] = __builtin_amdgcn_mfma_f32_16x16x32_bf16(a[mi], b[ni], acc[mi][ni], 0, 0, 0);
    }
  }
#pragma unroll
  for (int mi = 0; mi < 4; mi++)
#pragma unroll
    for (int ni = 0; ni < 2; ni++) {
      int row = m0 + wm + mi * 16 + quad * 4;
      int col = n0 + wn + ni * 16 + lane15;
#pragma unroll
      for (int r = 0; r < 4; r++)
        Of[(size_t)(row + r) * 1024 + col] = acc[mi][ni][r] + bias[col];
    }
}

// ---------------- flash attention v3: S^T formulation ----------------
// 512 blocks; bid & bid+256 -> complementary qtiles (q, 15-q) of the SAME bh.
// Wave owns 32 q rows. S^T = K·Q^T: q = lane15 (per-lane stats!), kv = quad*4+r.
// P stored packed b64 (XOR-swizzled 8B units), read back as contiguous b128 B-frags.
// O^T = V^T·P^T accumulated in C-layout: dh = quad*4+r, q = lane15.
__global__ __launch_bounds__(256, 2) void attn3(const u16* __restrict__ Q, const u16* __restrict__ Kg,
                                                const u16* __restrict__ Vtg, u16* __restrict__ ctx) {
  __shared__ __align__(16) u16 KsL[128 * 64];   // [kv][dh], 16B chunks ^(row&7)
  __shared__ __align__(16) u16 VtsL[64 * 128];  // [dh][kv], 16B chunks ^(row&15)
  __shared__ __align__(16) u16 Ps2[128 * 128];  // [q][kv], 8B units ^(2*(q&7)); wave-private rows
  int tid = threadIdx.x, wave = tid >> 6, lane = tid & 63;
  int lane15 = lane & 15, quad = lane >> 4;

  int bid = blockIdx.x;
  int pairIdx = bid & 255, half = bid >> 8;
  int p8 = pairIdx & 7, bh = pairIdx >> 3;
  int qt = half ? (15 - p8) : p8;
  int b = bh >> 4, h = bh & 15;
  int qbase = qt * 128;

  // Q B-frags (pre-scaled): B[n=q=lane15][k=dh=quad*8+j]
  bf16x8 qb[2][2];
#pragma unroll
  for (int mi = 0; mi < 2; mi++)
#pragma unroll
    for (int kc = 0; kc < 2; kc++)
      qb[mi][kc] = *(const bf16x8*)&Q[(size_t)(b * 2048 + qbase + wave * 32 + mi * 16 + lane15) * 1024 +
                                      h * 64 + kc * 32 + quad * 8];

  f32x4 oacc[4][2];  // O^T: [dh-tile][q-tile(mi)]
#pragma unroll
  for (int c4 = 0; c4 < 4; c4++)
#pragma unroll
    for (int mi = 0; mi < 2; mi++) oacc[c4][mi] = (f32x4){0.f, 0.f, 0.f, 0.f};
  float mrow[2] = {-3.0e38f, -3.0e38f}, lrow[2] = {0.f, 0.f};

  for (int t = 0; t <= qt; ++t) {
    int k0 = t * 128;
    __syncthreads();
#pragma unroll
    for (int i = 0; i < 4; i++) {
      int rbase = wave * 32 + i * 8;
      int rk = rbase + (lane >> 3);
      int ca = ((lane & 7) ^ (rk & 7)) * 8;
      GLOAD_LDS16(&Kg[(size_t)(b * 2048 + k0 + rk) * 1024 + h * 64 + ca], KsL + rbase * 64);
      int vbase = wave * 16 + i * 4;
      int rv = vbase + (lane >> 4);
      int cv = ((lane & 15) ^ (rv & 15)) * 8;
      GLOAD_LDS16(&Vtg[(size_t)(b * 1024 + h * 64 + rv) * 2048 + k0 + cv], VtsL + vbase * 128);
    }
    __syncthreads();

    // ---- S^T = K Q^T : per wave 128kv x 32q ----
    f32x4 s[2][8];
#pragma unroll
    for (int ct = 0; ct < 8; ct++) {
      int kr = ct * 16 + lane15;
      bf16x8 ka0 = *(const bf16x8*)(KsL + kr * 64 + ((quad ^ (kr & 7)) * 8));
      bf16x8 ka1 = *(const bf16x8*)(KsL + kr * 64 + (((4 + quad) ^ (kr & 7)) * 8));
#pragma unroll
      for (int mi = 0; mi < 2; mi++) {
        f32x4 z = (f32x4){0.f, 0.f, 0.f, 0.f};
        z = __builtin_amdgcn_mfma_f32_16x16x32_bf16(ka0, qb[mi][0], z, 0, 0, 0);
        z = __builtin_amdgcn_mfma_f32_16x16x32_bf16(ka1, qb[mi][1], z, 0, 0, 0);
        s[mi][ct] = z;
      }
    }

    bool diag = (t == qt);
#pragma unroll
    for (int mi = 0; mi < 2; mi++) {
      if (diag) {
        int ql = wave * 32 + mi * 16 + lane15;  // FIX: include wave*32 (local q within 128-row tile)
#pragma unroll
        for (int ct = 0; ct < 8; ct++)
#pragma unroll
          for (int r = 0; r < 4; r++)
            if (ct * 16 + quad * 4 + r > ql) s[mi][ct][r] = -3.0e38f;
      }
      // max over kv: in-register + 2 shfls (quads)
      float mx = mrow[mi];
#pragma unroll
      for (int ct = 0; ct < 8; ct++)
#pragma unroll
        for (int r = 0; r < 4; r++) mx = fmaxf(mx, s[mi][ct][r]);
      mx = fmaxf(mx, __shfl_xor(mx, 16));
      mx = fmaxf(mx, __shfl_xor(mx, 32));
      float sum = 0.f;
#pragma unroll
      for (int ct = 0; ct < 8; ct++)
#pragma unroll
        for (int r = 0; r < 4; r++) {
          float p = __builtin_amdgcn_exp2f(s[mi][ct][r] - mx);
          s[mi][ct][r] = p; sum += p;
        }
      sum += __shfl_xor(sum, 16);
      sum += __shfl_xor(sum, 32);
      float alpha = __builtin_amdgcn_exp2f(mrow[mi] - mx);
      lrow[mi] = lrow[mi] * alpha + sum;
      mrow[mi] = mx;
#pragma unroll
      for (int c4 = 0; c4 < 4; c4++)
#pragma unroll
        for (int r = 0; r < 4; r++) oacc[c4][mi][r] *= alpha;
      // P store: packed b64, 8B-unit XOR swizzle
      int prow = wave * 32 + mi * 16 + lane15;
      int sw = (lane15 & 7) << 1;
#pragma unroll
      for (int ct = 0; ct < 8; ct++) {
        unsigned int lo = pack_bf2(s[mi][ct][0], s[mi][ct][1]);
        unsigned int hi = pack_bf2(s[mi][ct][2], s[mi][ct][3]);
        int c8 = (ct * 4 + quad) ^ sw;
        *(uint2*)&Ps2[prow * 128 + c8 * 4] = (uint2){lo, hi};
      }
    }

    // ---- O^T += V^T P^T (wave-private P rows; compiler inserts lgkm wait) ----
#pragma unroll
    for (int kc = 0; kc < 4; kc++) {
      bf16x8 pb[2];
#pragma unroll
      for (int mi = 0; mi < 2; mi++) {
        int prow = wave * 32 + mi * 16 + lane15;
        int c8 = (kc * 8 + quad * 2) ^ ((lane15 & 7) << 1);
        pb[mi] = *(const bf16x8*)&Ps2[prow * 128 + c8 * 4];
      }
      int cb = kc * 4 + quad;
#pragma unroll
      for (int c4 = 0; c4 < 4; c4++) {
        int dh = c4 * 16 + lane15;
        bf16x8 va = *(const bf16x8*)(VtsL + dh * 128 + ((cb ^ (dh & 15)) * 8));
        oacc[c4][0] = __builtin_amdgcn_mfma_f32_16x16x32_bf16(va, pb[0], oacc[c4][0], 0, 0, 0);
        oacc[c4][1] = __builtin_amdgcn_mfma_f32_16x16x32_bf16(va, pb[1], oacc[c4][1], 0, 0, 0);
      }
    }
  }

  // ---- epilogue: ctx[b, q, h*64+dh] ; lane: q = mi*16+lane15, dh = c4*16+quad*4+r ----
#pragma unroll
  for (int mi = 0; mi < 2; mi++) {
    float inv = 1.0f / lrow[mi];
    size_t rowoff = (size_t)(b * 2048 + qbase + wave * 32 + mi * 16 + lane15) * 1024 + h * 64;
#pragma unroll
    for (int c4 = 0; c4 < 4; c4++) {
      ushort4 o;
      o.x = f2bf(oacc[c4][mi][0] * inv); o.y = f2bf(oacc[c4][mi][1] * inv);
      o.z = f2bf(oacc[c4][mi][2] * inv); o.w = f2bf(oacc[c4][mi][3] * inv);
      *(ushort4*)&ctx[rowoff + c4 * 16 + quad * 4] = o;
    }
  }
}

extern "C" void kernel_launch(void* const* d_in, const int* in_sizes, int n_in,
                              void* d_out, int out_size, void* d_ws, size_t ws_size,
                              hipStream_t stream) {
  const float* x  = (const float*)d_in[0];
  const float* Wq = (const float*)d_in[1];
  const float* Wk = (const float*)d_in[2];
  const float* Wv = (const float*)d_in[3];
  const float* Wo = (const float*)d_in[4];
  const float* bo = (const float*)d_in[5];
  float* out = (float*)d_out;
  char* ws = (char*)d_ws;
  const size_t MB = 1024 * 1024;
  u16* xb   = (u16*)(ws);
  u16* wqb  = (u16*)(ws +  8 * MB);
  u16* wkb  = (u16*)(ws + 10 * MB);
  u16* wvb  = (u16*)(ws + 12 * MB);
  u16* wob  = (u16*)(ws + 14 * MB);
  u16* Qb   = (u16*)(ws + 16 * MB);
  u16* Kb   = (u16*)(ws + 24 * MB);
  u16* Vtg  = (u16*)(ws + 32 * MB);  // V^T: [b,h,dh,n]
  u16* ctxb = (u16*)(ws + 40 * MB);

  conv_all<<<dim3(1024, 8), 256, 0, stream>>>(x, Wq, Wk, Wv, Wo, xb, wqb, wkb, wvb, wob);
  gemm_qkv<<<dim3(32, 8, 3), 256, 0, stream>>>(xb, wqb, wkb, wvb, Qb, Kb, Vtg);
  attn3<<<dim3(512), 256, 0, stream>>>(Qb, Kb, Vtg, ctxb);
  gemm_out<<<dim3(32, 16), 256, 0, stream>>>(ctxb, wob, out, bo);
}